// Round 9
// baseline (330.948 us; speedup 1.0000x reference)
//
#include <hip/hip_runtime.h>

typedef unsigned short u16;
typedef unsigned int   u32;
typedef float  f32x4  __attribute__((ext_vector_type(4)));
typedef __bf16 bf16x8 __attribute__((ext_vector_type(8)));
typedef u16    u16x8  __attribute__((ext_vector_type(8)));

#define NB     1024      // batch rows (M)
#define NN     8193      // output cols; true K = 8193
#define K2R    8256      // K padded to 129*64
#define NT     129       // K tiles of BK=64
#define ABF_LEN 16704    // a padded (true length 16385)
#define NFRAG  1032      // 16-wide Hankel fragment blocks (1KB each)

// workspace byte offsets (256-aligned)
#define OFF_BANDS 0u
#define OFF_ABF   74496u      // 16704*2 = 33408
#define OFF_BFRAG 108032u     // 1032*1024
#define OFF_UREV  1175040u    // 1024*8256*2

__device__ __forceinline__ u16 f2bf(float f) {
  u32 u = __builtin_bit_cast(u32, f);
  return (u16)((u + 0x7FFFu + ((u >> 16) & 1u)) >> 16);
}
__device__ __forceinline__ float bf2f(u16 h) {
  u32 u = ((u32)h) << 16;
  return __builtin_bit_cast(float, u);
}

// ---------------- kernel a construction ----------------
__global__ void k_bands(const float* __restrict__ x,
                        const float* __restrict__ W1, const float* __restrict__ b1,
                        const float* __restrict__ W2, const float* __restrict__ b2,
                        const float* __restrict__ W3, const float* __restrict__ b3,
                        float* __restrict__ bands) {
  const int j = blockIdx.y;
  __shared__ float w2s[4096];
  __shared__ float w1s[64], b1s[64], b2s[64], w3s[64];
  for (int i = threadIdx.x; i < 4096; i += 256) w2s[i] = W2[j * 4096 + i];
  if (threadIdx.x < 64) {
    w1s[threadIdx.x] = W1[j * 64 + threadIdx.x];
    b1s[threadIdx.x] = b1[j * 64 + threadIdx.x];
    b2s[threadIdx.x] = b2[j * 64 + threadIdx.x];
    w3s[threadIdx.x] = W3[j * 64 + threadIdx.x];
  }
  __syncthreads();
  const int k = blockIdx.x * 256 + threadIdx.x;
  if (k >= 2049) return;
  const float xc = x[8 * k];
  float h1[64];
  #pragma unroll
  for (int o = 0; o < 64; ++o) h1[o] = tanhf(w1s[o] * xc + b1s[o]);
  float outv = b3[j];
  for (int o = 0; o < 64; ++o) {
    float a0 = 0.f, a1 = 0.f, a2 = 0.f, a3 = 0.f;
    #pragma unroll
    for (int c = 0; c < 64; c += 4) {
      a0 += w2s[o * 64 + c] * h1[c];
      a1 += w2s[o * 64 + c + 1] * h1[c + 1];
      a2 += w2s[o * 64 + c + 2] * h1[c + 2];
      a3 += w2s[o * 64 + c + 3] * h1[c + 3];
    }
    outv += w3s[o] * tanhf(b2s[o] + ((a0 + a1) + (a2 + a3)));
  }
  bands[j * 2049 + k] = outv;
}

// fused interp: lvl1 (LDS) -> lvl2 (LDS) -> lvl3 (abf, bf16). One block.
__global__ void k_interp(const float* __restrict__ bands, u16* __restrict__ abf) {
  __shared__ float s1[4097];
  __shared__ float s2[8193];
  const int tid = threadIdx.x;
  const float* bd0 = bands;
  const float* bd1 = bands + 2049;
  const float* bd2 = bands + 2 * 2049;
  for (int i = tid; i < 4097; i += 1024) {
    float v = (i & 1) ? 0.5f * (bd0[i >> 1] + bd0[(i >> 1) + 1]) : bd0[i >> 1];
    if (i >= 512 && i < 2561) v = bd1[i - 512];
    s1[i] = v;
  }
  __syncthreads();
  for (int i = tid; i < 8193; i += 1024) {
    float v = (i & 1) ? 0.5f * (s1[i >> 1] + s1[(i >> 1) + 1]) : s1[i >> 1];
    if (i >= 1024 && i < 3073) v = bd2[i - 1024];
    s2[i] = v;
  }
  __syncthreads();
  for (int i = tid; i < ABF_LEN; i += 1024) {
    float v = 0.f;
    if (i <= 16384)
      v = (i & 1) ? 0.5f * (s2[i >> 1] + s2[(i >> 1) + 1]) : s2[i >> 1];
    abf[i] = f2bf(v);
  }
}

// urev[b][j] = bf16(u[b][8192-j]) for j<=8192 else 0 (row stride K2R).
// Vectorized: aligned float4 pair covering ub[e-8..e-1] + scalar ub[e].
__global__ void k_urev(const float* __restrict__ u, u16* __restrict__ urev) {
  const int b = blockIdx.y;
  const int c = blockIdx.x * 256 + threadIdx.x;
  if (c >= K2R / 8) return;
  const int j0 = c * 8;
  const float* ub = u + (size_t)b * NN;
  u16x8 v;
  if (j0 < 8192) {
    const int e = 8192 - j0;           // e >= 8, e-8 is 8-aligned
    const float4 q0 = *(const float4*)&ub[e - 8];
    const float4 q1 = *(const float4*)&ub[e - 4];
    const float  s  = ub[e];
    v[0] = f2bf(s);
    v[1] = f2bf(q1.w); v[2] = f2bf(q1.z); v[3] = f2bf(q1.y); v[4] = f2bf(q1.x);
    v[5] = f2bf(q0.w); v[6] = f2bf(q0.z); v[7] = f2bf(q0.y);
  } else if (j0 == 8192) {
    v[0] = f2bf(ub[0]);
    #pragma unroll
    for (int r = 1; r < 8; ++r) v[r] = 0;
  } else {
    #pragma unroll
    for (int r = 0; r < 8; ++r) v[r] = 0;
  }
  *(u16x8*)&urev[(size_t)b * K2R + j0] = v;
}

// 16-wide Hankel fragments (R1/R6/R8-proven) for mfma_16x16x32 B-operand:
// Bfrag[f][lane][idx] = abf[16f + (lane&15) + 8*(lane>>4) + idx]
__global__ void k_bfrag(const u16* __restrict__ abf, u16* __restrict__ bfr) {
  const int g = blockIdx.x * 256 + threadIdx.x;
  if (g >= NFRAG * 64) return;
  const int t = g >> 6, l = g & 63;
  const int s = 16 * t + (l & 15) + ((l >> 4) << 3);
  u16x8 v;
  #pragma unroll
  for (int r = 0; r < 8; ++r) v[r] = abf[s + r];
  *(u16x8*)&bfr[(size_t)g * 8] = v;
}

// column 8192: w[b,8192] = sum_j urev[b,j] * abf[8192+j]
__global__ void k_lastcol(const u16* __restrict__ urev, const u16* __restrict__ abf,
                          float* __restrict__ out) {
  const int b = blockIdx.x;
  const int tid = threadIdx.x;
  float s = 0.f;
  #pragma unroll
  for (int it = 0; it < 5; ++it) {
    const int c = tid + 256 * it;
    if (c < K2R / 8) {
      u16x8 uv = *(const u16x8*)&urev[(size_t)b * K2R + c * 8];
      u16x8 av = *(const u16x8*)&abf[8192 + c * 8];
      #pragma unroll
      for (int r = 0; r < 8; ++r) s += bf2f(uv[r]) * bf2f(av[r]);
    }
  }
  #pragma unroll
  for (int off = 32; off >= 1; off >>= 1) s += __shfl_xor(s, off, 64);
  __shared__ float red[4];
  if ((tid & 63) == 0) red[tid >> 6] = s;
  __syncthreads();
  if (tid == 0) out[(size_t)b * NN + 8192] = red[0] + red[1] + red[2] + red[3];
}

// ---------------- main Hankel GEMM: zero-LDS, zero-barrier ----------------
// BM=128 x BN=128 x BK=64, 256 threads (4 waves 2Mx2N), 16x16x32 MFMA.
// BOTH operands load straight from the L2-resident tables into registers:
//   A: per-lane dwordx4 at urev[row=(lane&15)+16m][kslice=(lane>>4)*8+32kk]
//      (64 lanes = 16 x 64B contiguous segments; per-XCD panel is L2-resident)
//   B: R7/R8-proven coalesced 1KB fragment loads from bfrag.
// No __shared__, no s_barrier, no manual waitcnt: each wave is an independent
// {14 loads, 16 MFMA} stream, 2-deep register double-buffered; the compiler
// inserts exact vmcnt waits. Without lockstep barriers the 2 waves/SIMD
// (2 blocks/CU) drift into anti-phase and hide each other's load latency.
// Fragment math / C-write byte-identical to R8's verified kernel.
__global__ __launch_bounds__(256, 2) void k_gemm(const u16* __restrict__ urev,
                                                 const u16* __restrict__ bfrag,
                                                 float* __restrict__ out) {
  const int tid  = threadIdx.x;
  const int lane = tid & 63;
  const int wid  = tid >> 6;
  const int wr   = wid >> 1;   // 0..1  (64-row slice)
  const int wc   = wid & 1;    // 0..1  (64-col slice)

  // 512 blocks: by = XCD id (round-robin), 64 bx share one 2.1MB A-panel per XCD
  const int by = blockIdx.x & 7;
  const int bx = blockIdx.x >> 3;
  const int b0 = by * 128;
  const int i0 = bx * 128;
  const int F0 = bx * 8;       // base fragment at t=0

  // A: lane base pointer at row (b0 + wr*64 + lane&15), k-offset (lane>>4)*8
  const u16* aRow = urev + (size_t)(b0 + (wr << 6) + (lane & 15)) * K2R + ((lane >> 4) << 3);
  // B: per-wave fragment pointer; frag(t, n, kk) = F0 + 4t + 4wc + n + 2kk
  const u16* bW = bfrag + (((size_t)(F0 + (wc << 2))) << 9) + (lane << 3);

  f32x4 acc[4][4] = {};
  bf16x8 aX[8], aY[8], bX[6], bY[6];

  auto loadA = [&](bf16x8* ar, int t) {
    const u16* p = aRow + (t << 6);
    #pragma unroll
    for (int kk = 0; kk < 2; ++kk)
      #pragma unroll
      for (int m = 0; m < 4; ++m)
        ar[(kk << 2) + m] = *reinterpret_cast<const bf16x8*>(
            p + (size_t)m * (16 * K2R) + (kk << 5));
  };
  auto loadB = [&](bf16x8* br, int t) {
    const u16* p = bW + ((size_t)t << 11);   // +4t fragments
    #pragma unroll
    for (int j = 0; j < 6; ++j)
      br[j] = *reinterpret_cast<const bf16x8*>(p + (j << 9));
  };
  auto mm = [&](const bf16x8* ar, const bf16x8* br) {
    #pragma unroll
    for (int kk = 0; kk < 2; ++kk)
      #pragma unroll
      for (int m = 0; m < 4; ++m)
        #pragma unroll
        for (int n = 0; n < 4; ++n)
          acc[m][n] = __builtin_amdgcn_mfma_f32_16x16x32_bf16(
              ar[(kk << 2) + m], br[n + (kk << 1)], acc[m][n], 0, 0, 0);
  };

  // prologue: tile 0 -> X bank
  loadA(aX, 0);
  loadB(bX, 0);

  // main loop, 2-deep register pipeline (tiles 0..127 in pairs; NT-1=128 even)
  #pragma unroll 1
  for (int t = 0; t < NT - 1; t += 2) {
    loadA(aY, t + 1); loadB(bY, t + 1);
    mm(aX, bX);
    loadA(aX, t + 2); loadB(bX, t + 2);   // t+2 <= 128, in bounds
    mm(aY, bY);
  }
  mm(aX, bX);  // tile 128

  // C-write (R1/R8-proven 16x16 layout): col = lane&15 (+16n), row = 4*(lane>>4)+r
  #pragma unroll
  for (int n = 0; n < 4; ++n) {
    const int col = i0 + (wc << 6) + (n << 4) + (lane & 15);  // max 8191 < NN
    #pragma unroll
    for (int m = 0; m < 4; ++m) {
      const int rowb = b0 + (wr << 6) + (m << 4) + ((lane >> 4) << 2);
      float* o = out + (size_t)rowb * NN + col;
      #pragma unroll
      for (int r = 0; r < 4; ++r) o[(size_t)r * NN] = acc[m][n][r];
    }
  }
}

extern "C" void kernel_launch(void* const* d_in, const int* in_sizes, int n_in,
                              void* d_out, int out_size, void* d_ws, size_t ws_size,
                              hipStream_t stream) {
  (void)in_sizes; (void)n_in; (void)out_size; (void)ws_size;
  const float* u  = (const float*)d_in[0];
  const float* x  = (const float*)d_in[1];
  const float* W1 = (const float*)d_in[2];
  const float* b1 = (const float*)d_in[3];
  const float* W2 = (const float*)d_in[4];
  const float* b2 = (const float*)d_in[5];
  const float* W3 = (const float*)d_in[6];
  const float* b3 = (const float*)d_in[7];
  float* out = (float*)d_out;
  char*  ws  = (char*)d_ws;

  float* bands = (float*)(ws + OFF_BANDS);
  u16*   abf   = (u16*)(ws + OFF_ABF);
  u16*   bfr   = (u16*)(ws + OFF_BFRAG);
  u16*   urev  = (u16*)(ws + OFF_UREV);

  k_bands<<<dim3(9, 3), 256, 0, stream>>>(x, W1, b1, W2, b2, W3, b3, bands);
  k_interp<<<1, 1024, 0, stream>>>(bands, abf);
  k_urev<<<dim3(5, 1024), 256, 0, stream>>>(u, urev);
  k_bfrag<<<258, 256, 0, stream>>>(abf, bfr);
  k_lastcol<<<1024, 256, 0, stream>>>(urev, abf, out);
  k_gemm<<<512, 256, 0, stream>>>(urev, bfr, out);
}

// Round 10
// 293.865 us; speedup vs baseline: 1.1262x; 1.1262x over previous
//
#include <hip/hip_runtime.h>

#define NN  8193       // output cols per row; u length
#define FN  16384      // complex FFT length (real conv length 32768)

// workspace byte offsets (256-aligned)
#define OFF_BANDS 0u        // 3*2049*4 = 24588
#define OFF_AF32  24832u    // 16385*4 = 65540
#define OFF_AHAT  90624u    // 16385*8 = 131080 (float2, natural order, 1/16384-scaled)

__device__ __forceinline__ float2 cmul(float2 a, float2 b) {
  return make_float2(a.x * b.x - a.y * b.y, a.x * b.y + a.y * b.x);
}

// base-4 digit reversal of 7 digits (14 bits)
__device__ __forceinline__ int rev4_14(int k) {
  int r = 0;
  #pragma unroll
  for (int i = 0; i < 7; ++i) { r = (r << 2) | (k & 3); k >>= 2; }
  return r;
}

#define W_STEP (-3.83495197e-4f)   // -2*pi/16384
#define TAU_STEP (1.91747598e-4f)  //  pi/16384

// In-place DIF radix-4 forward FFT over Z[FN]: natural in -> digit-reversed out.
// Verified butterfly (N=4 check): p-th output = sum_q x[j+qQ] w4^{pq}, stored at
// j+pQ, twiddled by wS^{jp}.
__device__ void fft_fwd(float2* Z, int tid, int nthr) {
  #pragma unroll 1
  for (int st = 0; st < 7; ++st) {
    const int qsh = 12 - 2 * st;      // log2(Q), Q = quarter span
    const int Q = 1 << qsh;
    const int m = 1 << (2 * st);      // N / S
    #pragma unroll 1
    for (int idx = tid; idx < FN / 4; idx += nthr) {
      const int j = idx & (Q - 1);
      const int base = ((idx >> qsh) << (qsh + 2)) + j;
      float2 c0 = Z[base], c1 = Z[base + Q], c2 = Z[base + 2 * Q], c3 = Z[base + 3 * Q];
      float2 t0 = make_float2(c0.x + c2.x, c0.y + c2.y);
      float2 t1 = make_float2(c0.x - c2.x, c0.y - c2.y);
      float2 t2 = make_float2(c1.x + c3.x, c1.y + c3.y);
      float2 t3 = make_float2(c1.y - c3.y, -(c1.x - c3.x));   // -i*(c1-c3)
      float sn, cs;
      __sincosf((float)(j * m) * W_STEP, &sn, &cs);
      float2 w1 = make_float2(cs, sn);
      float2 w2 = cmul(w1, w1);
      float2 w3 = cmul(w2, w1);
      Z[base]         = make_float2(t0.x + t2.x, t0.y + t2.y);
      Z[base + Q]     = cmul(w1, make_float2(t1.x + t3.x, t1.y + t3.y));
      Z[base + 2 * Q] = cmul(w2, make_float2(t0.x - t2.x, t0.y - t2.y));
      Z[base + 3 * Q] = cmul(w3, make_float2(t1.x - t3.x, t1.y - t3.y));
    }
    __syncthreads();
  }
}

// Exact adjoint of fft_fwd (unscaled inverse): digit-reversed in -> natural out.
// Each stage is G^H of the matching forward stage: conj-twiddle inputs, then
// conjugate DFT4; stage order mirrored (S=4 first).
__device__ void fft_inv(float2* Z, int tid, int nthr) {
  #pragma unroll 1
  for (int st = 6; st >= 0; --st) {
    const int qsh = 12 - 2 * st;
    const int Q = 1 << qsh;
    const int m = 1 << (2 * st);
    #pragma unroll 1
    for (int idx = tid; idx < FN / 4; idx += nthr) {
      const int j = idx & (Q - 1);
      const int base = ((idx >> qsh) << (qsh + 2)) + j;
      float2 u0 = Z[base], u1 = Z[base + Q], u2 = Z[base + 2 * Q], u3 = Z[base + 3 * Q];
      float sn, cs;
      __sincosf((float)(j * m) * W_STEP, &sn, &cs);
      float2 w1 = make_float2(cs, -sn);              // conj of forward twiddle
      float2 w2 = cmul(w1, w1);
      float2 w3 = cmul(w2, w1);
      u1 = cmul(w1, u1);
      u2 = cmul(w2, u2);
      u3 = cmul(w3, u3);
      float2 s0 = make_float2(u0.x + u2.x, u0.y + u2.y);
      float2 s1 = make_float2(u0.x - u2.x, u0.y - u2.y);
      float2 s2 = make_float2(u1.x + u3.x, u1.y + u3.y);
      float2 s3 = make_float2(-(u1.y - u3.y), u1.x - u3.x);  // +i*(u1-u3)
      Z[base]         = make_float2(s0.x + s2.x, s0.y + s2.y);
      Z[base + Q]     = make_float2(s1.x + s3.x, s1.y + s3.y);
      Z[base + 2 * Q] = make_float2(s0.x - s2.x, s0.y - s2.y);
      Z[base + 3 * Q] = make_float2(s1.x - s3.x, s1.y - s3.y);
    }
    __syncthreads();
  }
}

// ---------------- kernel a construction (unchanged math, fp32 out) ----------
__global__ void k_bands(const float* __restrict__ x,
                        const float* __restrict__ W1, const float* __restrict__ b1,
                        const float* __restrict__ W2, const float* __restrict__ b2,
                        const float* __restrict__ W3, const float* __restrict__ b3,
                        float* __restrict__ bands) {
  const int j = blockIdx.y;
  __shared__ float w2s[4096];
  __shared__ float w1s[64], b1s[64], b2s[64], w3s[64];
  for (int i = threadIdx.x; i < 4096; i += 256) w2s[i] = W2[j * 4096 + i];
  if (threadIdx.x < 64) {
    w1s[threadIdx.x] = W1[j * 64 + threadIdx.x];
    b1s[threadIdx.x] = b1[j * 64 + threadIdx.x];
    b2s[threadIdx.x] = b2[j * 64 + threadIdx.x];
    w3s[threadIdx.x] = W3[j * 64 + threadIdx.x];
  }
  __syncthreads();
  const int k = blockIdx.x * 256 + threadIdx.x;
  if (k >= 2049) return;
  const float xc = x[8 * k];
  float h1[64];
  #pragma unroll
  for (int o = 0; o < 64; ++o) h1[o] = tanhf(w1s[o] * xc + b1s[o]);
  float outv = b3[j];
  for (int o = 0; o < 64; ++o) {
    float a0 = 0.f, a1 = 0.f, a2 = 0.f, a3 = 0.f;
    #pragma unroll
    for (int c = 0; c < 64; c += 4) {
      a0 += w2s[o * 64 + c] * h1[c];
      a1 += w2s[o * 64 + c + 1] * h1[c + 1];
      a2 += w2s[o * 64 + c + 2] * h1[c + 2];
      a3 += w2s[o * 64 + c + 3] * h1[c + 3];
    }
    outv += w3s[o] * tanhf(b2s[o] + ((a0 + a1) + (a2 + a3)));
  }
  bands[j * 2049 + k] = outv;
}

// fused interp chain -> a in fp32, length 16385
__global__ void k_interp(const float* __restrict__ bands, float* __restrict__ af32) {
  __shared__ float s1[4097];
  __shared__ float s2[8193];
  const int tid = threadIdx.x;
  const float* bd0 = bands;
  const float* bd1 = bands + 2049;
  const float* bd2 = bands + 2 * 2049;
  for (int i = tid; i < 4097; i += 1024) {
    float v = (i & 1) ? 0.5f * (bd0[i >> 1] + bd0[(i >> 1) + 1]) : bd0[i >> 1];
    if (i >= 512 && i < 2561) v = bd1[i - 512];
    s1[i] = v;
  }
  __syncthreads();
  for (int i = tid; i < 8193; i += 1024) {
    float v = (i & 1) ? 0.5f * (s1[i >> 1] + s1[(i >> 1) + 1]) : s1[i >> 1];
    if (i >= 1024 && i < 3073) v = bd2[i - 1024];
    s2[i] = v;
  }
  __syncthreads();
  for (int i = tid; i < 16385; i += 1024) {
    float v = (i & 1) ? 0.5f * (s2[i >> 1] + s2[(i >> 1) + 1]) : s2[i >> 1];
    af32[i] = v;
  }
}

// A-hat: Ahat[k] = rfft_32768(a_pad)[k] / 16384, natural order, k in [0,16384].
// One block. Packed even/odd cfft + standard unpack (E + tau*O).
__global__ __launch_bounds__(512, 1) void k_ahat(const float* __restrict__ af32,
                                                 float2* __restrict__ Ahat) {
  __shared__ float2 Z[FN];
  const int tid = threadIdx.x;
  for (int n = tid; n < FN; n += 512) {
    float2 v = make_float2(0.f, 0.f);
    if (n < 8192)       v = make_float2(af32[2 * n], af32[2 * n + 1]);
    else if (n == 8192) v = make_float2(af32[16384], 0.f);
    Z[n] = v;
  }
  __syncthreads();
  fft_fwd(Z, tid, 512);
  const float sc = 1.0f / 16384.0f;
  for (int k = tid; k <= 16384; k += 512) {
    float2 A;
    if (k == 0) {
      float2 z0 = Z[0];
      A = make_float2((z0.x + z0.y) * sc, 0.f);
    } else if (k == 16384) {
      float2 z0 = Z[0];
      A = make_float2((z0.x - z0.y) * sc, 0.f);
    } else if (k == 8192) {
      float2 z8 = Z[rev4_14(8192)];
      A = make_float2(z8.x * sc, -z8.y * sc);       // conj(Z[8192]) * sc
    } else {
      const int kc = 16384 - k;
      float2 Zk = Z[rev4_14(k)];
      float2 Zc = Z[rev4_14(kc)];
      float2 E = make_float2(0.5f * (Zk.x + Zc.x), 0.5f * (Zk.y - Zc.y));
      float2 D = make_float2(Zk.x - Zc.x, Zk.y + Zc.y);   // Zk - conj(Zc)
      float2 O = make_float2(0.5f * D.y, -0.5f * D.x);    // -i/2 * D
      float sn, cs;
      __sincosf((float)k * TAU_STEP, &sn, &cs);
      float2 tau = make_float2(cs, -sn);                  // e^{-i pi k / 16384}
      float2 tO = cmul(tau, O);
      A = make_float2((E.x + tO.x) * sc, (E.y + tO.y) * sc);
    }
    Ahat[k] = A;
  }
}

// Main conv kernel: one batch row per block.
// out[b,i] = sum_m a[m] * utilde[(i-m) mod 32768], utilde[0]=u[8192],
// utilde[24576+r]=u[r] (r<8192) -> exact Hankel matvec for i in [0,8193).
__global__ __launch_bounds__(512, 1) void k_conv(const float* __restrict__ u,
                                                 const float2* __restrict__ Ahat,
                                                 float* __restrict__ out) {
  __shared__ float2 Z[FN];
  const int tid = threadIdx.x;
  const int b = blockIdx.x;
  const float* ub = u + (size_t)b * NN;

  // pack utilde (even/odd) into complex Z
  for (int n = tid; n < FN; n += 512) {
    float2 v = make_float2(0.f, 0.f);
    if (n == 0)          v = make_float2(ub[8192], 0.f);
    else if (n >= 12288) {
      const int m = n - 12288;
      v = make_float2(ub[2 * m], ub[2 * m + 1]);
    }
    Z[n] = v;
  }
  __syncthreads();

  fft_fwd(Z, tid, 512);

  // spectral: unpack (rfft), multiply by Ahat, repack (irfft prep) — in the
  // digit-reversed domain. Pairs (k, 16384-k) are bijective in rev-space:
  // each thread owns its slots, no barrier inside.
  for (int i = tid; i < 8192; i += 512) {
    if (i == 0) {
      // k = 0 and k = 16384 edges (all real)
      float2 z0 = Z[0];
      float X0 = z0.x + z0.y;
      float XN = z0.x - z0.y;
      float Y0 = X0 * Ahat[0].x;
      float YN = XN * Ahat[16384].x;
      Z[0] = make_float2(0.5f * (Y0 + YN), 0.5f * (Y0 - YN));
      // k = 8192 self-paired: X = conj(Z), Y = X*A, W = conj(Y)
      const int r8 = rev4_14(8192);
      float2 z8 = Z[r8];
      float2 X8 = make_float2(z8.x, -z8.y);
      float2 Y8 = cmul(X8, Ahat[8192]);
      Z[r8] = make_float2(Y8.x, -Y8.y);
    } else {
      const int k = i, kc = 16384 - i;
      const int rk = rev4_14(k), rkc = rev4_14(kc);
      float2 Zk = Z[rk], Zc = Z[rkc];
      // E = (Zk + conj(Zc))/2 ; O = -i/2 (Zk - conj(Zc))
      float2 E = make_float2(0.5f * (Zk.x + Zc.x), 0.5f * (Zk.y - Zc.y));
      float2 D = make_float2(Zk.x - Zc.x, Zk.y + Zc.y);
      float2 O = make_float2(0.5f * D.y, -0.5f * D.x);
      float sn, cs;
      __sincosf((float)k * TAU_STEP, &sn, &cs);
      float2 tau = make_float2(cs, -sn);          // e^{-i pi k/N}
      float2 tO = cmul(tau, O);
      float2 Xk = make_float2(E.x + tO.x, E.y + tO.y);
      float2 Xc = make_float2(E.x - tO.x, -(E.y - tO.y));   // conj(E - tau*O)
      float2 Yk = cmul(Xk, Ahat[k]);
      float2 Y2 = cmul(Xc, Ahat[kc]);
      // Ep = (Yk + conj(Y2))/2 ; Op = conj(tau) * (Yk - conj(Y2))/2
      float2 Ep = make_float2(0.5f * (Yk.x + Y2.x), 0.5f * (Yk.y - Y2.y));
      float2 D2 = make_float2(0.5f * (Yk.x - Y2.x), 0.5f * (Yk.y + Y2.y));
      float2 taub = make_float2(cs, sn);          // e^{+i pi k/N}
      float2 Op = cmul(taub, D2);
      // W[k] = Ep + i*Op ; W[kc] = conj(Ep) + i*conj(Op)
      Z[rk]  = make_float2(Ep.x - Op.y, Ep.y + Op.x);
      Z[rkc] = make_float2(Ep.x + Op.y, -Ep.y + Op.x);
    }
  }
  __syncthreads();

  fft_inv(Z, tid, 512);   // includes trailing barrier

  // output: c[2n] = Re w[n], c[2n+1] = Im w[n]; need c[0..8192]
  float* ob = out + (size_t)b * NN;
  for (int n = tid; n <= 4096; n += 512) {
    float2 w = Z[n];
    if (n < 4096) {
      ob[2 * n]     = w.x;
      ob[2 * n + 1] = w.y;
    } else {
      ob[8192] = w.x;
    }
  }
}

extern "C" void kernel_launch(void* const* d_in, const int* in_sizes, int n_in,
                              void* d_out, int out_size, void* d_ws, size_t ws_size,
                              hipStream_t stream) {
  (void)in_sizes; (void)n_in; (void)out_size; (void)ws_size;
  const float* u  = (const float*)d_in[0];
  const float* x  = (const float*)d_in[1];
  const float* W1 = (const float*)d_in[2];
  const float* b1 = (const float*)d_in[3];
  const float* W2 = (const float*)d_in[4];
  const float* b2 = (const float*)d_in[5];
  const float* W3 = (const float*)d_in[6];
  const float* b3 = (const float*)d_in[7];
  float* out = (float*)d_out;
  char*  ws  = (char*)d_ws;

  float*  bands = (float*)(ws + OFF_BANDS);
  float*  af32  = (float*)(ws + OFF_AF32);
  float2* Ahat  = (float2*)(ws + OFF_AHAT);

  k_bands<<<dim3(9, 3), 256, 0, stream>>>(x, W1, b1, W2, b2, W3, b3, bands);
  k_interp<<<1, 1024, 0, stream>>>(bands, af32);
  k_ahat<<<1, 512, 0, stream>>>(af32, Ahat);
  k_conv<<<1024, 512, 0, stream>>>(u, Ahat, out);
}

// Round 11
// 291.987 us; speedup vs baseline: 1.1334x; 1.0064x over previous
//
#include <hip/hip_runtime.h>

#define NN  8193       // output cols per row; u length
#define FN  16384      // complex FFT length (real conv length 32768)

// LDS swizzle-pad: breaks the 4/16-way bank conflicts of strided radix-4
// stages; injective (strictly increasing). Max ZIDX(16383) = 17661.
#define ZIDX(i) ((i) + ((i) >> 4) + ((i) >> 6))
#define ZPAD 17664

// workspace byte offsets (256-aligned)
#define OFF_BANDS 0u        // 3*2049*4 = 24588
#define OFF_AF32  24832u    // 16385*4 = 65540
#define OFF_AHAT  90624u    // 16385*8 = 131080
#define OFF_TW    221952u   // 12288*8 = 98304  (w_N^e, e in [0,12288))
#define OFF_TAU   320256u   // 16385*8 = 131080 (exp(-i pi k/N), k in [0,16384])

__device__ __forceinline__ float2 cmul(float2 a, float2 b) {
  return make_float2(a.x * b.x - a.y * b.y, a.x * b.y + a.y * b.x);
}
__device__ __forceinline__ float2 cadd(float2 a, float2 b) { return make_float2(a.x + b.x, a.y + b.y); }
__device__ __forceinline__ float2 csub(float2 a, float2 b) { return make_float2(a.x - b.x, a.y - b.y); }

// base-4 digit reversal of 7 digits (14 bits)
__device__ __forceinline__ int rev4_14(int k) {
  int r = 0;
  #pragma unroll
  for (int i = 0; i < 7; ++i) { r = (r << 2) | (k & 3); k >>= 2; }
  return r;
}

// ---- fused double radix-4 stage, forward (stages sA, sA+1 of R10's DIF) ----
// Q1 = 4^(6-sA), M1 = 4^sA. Thread owns (b1, j2); its 16-element load/store
// sets coincide -> in-place, no intra-pass sync. Butterfly formulas identical
// to the R10-verified single stages.
template<int Q1, int M1>
__device__ __forceinline__ void ds_fwd(float2* Z, const float2* __restrict__ tw,
                                       int tid, int nthr) {
  constexpr int Q2 = Q1 >> 2;
  constexpr int M2 = M1 << 2;
  for (int t = tid; t < 1024; t += nthr) {
    const int b1 = t / Q2;
    const int j2 = t & (Q2 - 1);
    const int base = b1 * 4 * Q1 + j2;
    float2 c[4][4];  // [q1][q2]
    #pragma unroll
    for (int q1 = 0; q1 < 4; ++q1)
      #pragma unroll
      for (int q2 = 0; q2 < 4; ++q2)
        c[q1][q2] = Z[ZIDX(base + q2 * Q2 + q1 * Q1)];
    // stage A: across q1, twiddle exp (j2 + q2*Q2)*M1
    #pragma unroll
    for (int q2 = 0; q2 < 4; ++q2) {
      const int e = (j2 + q2 * Q2) * M1;
      const float2 w1 = tw[e], w2 = tw[2 * e], w3 = tw[3 * e];
      float2 c0 = c[0][q2], c1 = c[1][q2], c2 = c[2][q2], c3 = c[3][q2];
      float2 t0 = cadd(c0, c2), t1 = csub(c0, c2), t2 = cadd(c1, c3);
      float2 t3 = make_float2(c1.y - c3.y, -(c1.x - c3.x));   // -i*(c1-c3)
      c[0][q2] = cadd(t0, t2);
      c[1][q2] = cmul(w1, cadd(t1, t3));
      c[2][q2] = cmul(w2, csub(t0, t2));
      c[3][q2] = cmul(w3, csub(t1, t3));
    }
    // stage B: across q2, twiddle exp j2*M2 (same for all p1)
    const int e2 = j2 * M2;
    const float2 v1 = tw[e2], v2 = tw[2 * e2], v3 = tw[3 * e2];
    #pragma unroll
    for (int p1 = 0; p1 < 4; ++p1) {
      float2 c0 = c[p1][0], c1 = c[p1][1], c2 = c[p1][2], c3 = c[p1][3];
      float2 t0 = cadd(c0, c2), t1 = csub(c0, c2), t2 = cadd(c1, c3);
      float2 t3 = make_float2(c1.y - c3.y, -(c1.x - c3.x));
      c[p1][0] = cadd(t0, t2);
      c[p1][1] = cmul(v1, cadd(t1, t3));
      c[p1][2] = cmul(v2, csub(t0, t2));
      c[p1][3] = cmul(v3, csub(t1, t3));
    }
    #pragma unroll
    for (int p1 = 0; p1 < 4; ++p1)
      #pragma unroll
      for (int p2 = 0; p2 < 4; ++p2)
        Z[ZIDX(base + p1 * Q1 + p2 * Q2)] = c[p1][p2];
  }
}

// ---- fused double stage, exact adjoint (undoes sA+1 then sA) ----
template<int Q1, int M1>
__device__ __forceinline__ void ds_inv(float2* Z, const float2* __restrict__ tw,
                                       int tid, int nthr) {
  constexpr int Q2 = Q1 >> 2;
  constexpr int M2 = M1 << 2;
  for (int t = tid; t < 1024; t += nthr) {
    const int b1 = t / Q2;
    const int j2 = t & (Q2 - 1);
    const int base = b1 * 4 * Q1 + j2;
    float2 c[4][4];  // [p1][p2]
    #pragma unroll
    for (int p1 = 0; p1 < 4; ++p1)
      #pragma unroll
      for (int p2 = 0; p2 < 4; ++p2)
        c[p1][p2] = Z[ZIDX(base + p1 * Q1 + p2 * Q2)];
    // undo stage B: conj twiddle exp j2*M2, conj DFT4 across p2
    const int e2 = j2 * M2;
    float2 v1 = tw[e2], v2 = tw[2 * e2], v3 = tw[3 * e2];
    v1.y = -v1.y; v2.y = -v2.y; v3.y = -v3.y;
    #pragma unroll
    for (int p1 = 0; p1 < 4; ++p1) {
      float2 u0 = c[p1][0];
      float2 u1 = cmul(v1, c[p1][1]);
      float2 u2 = cmul(v2, c[p1][2]);
      float2 u3 = cmul(v3, c[p1][3]);
      float2 s0 = cadd(u0, u2), s1 = csub(u0, u2), s2 = cadd(u1, u3);
      float2 s3 = make_float2(-(u1.y - u3.y), u1.x - u3.x);  // +i*(u1-u3)
      c[p1][0] = cadd(s0, s2);
      c[p1][1] = cadd(s1, s3);
      c[p1][2] = csub(s0, s2);
      c[p1][3] = csub(s1, s3);
    }
    // undo stage A: conj twiddle exp (j2+q2*Q2)*M1, conj DFT4 across p1
    #pragma unroll
    for (int q2 = 0; q2 < 4; ++q2) {
      const int e = (j2 + q2 * Q2) * M1;
      float2 w1 = tw[e], w2 = tw[2 * e], w3 = tw[3 * e];
      w1.y = -w1.y; w2.y = -w2.y; w3.y = -w3.y;
      float2 u0 = c[0][q2];
      float2 u1 = cmul(w1, c[1][q2]);
      float2 u2 = cmul(w2, c[2][q2]);
      float2 u3 = cmul(w3, c[3][q2]);
      float2 s0 = cadd(u0, u2), s1 = csub(u0, u2), s2 = cadd(u1, u3);
      float2 s3 = make_float2(-(u1.y - u3.y), u1.x - u3.x);
      c[0][q2] = cadd(s0, s2);
      c[1][q2] = cadd(s1, s3);
      c[2][q2] = csub(s0, s2);
      c[3][q2] = csub(s1, s3);
    }
    #pragma unroll
    for (int q1 = 0; q1 < 4; ++q1)
      #pragma unroll
      for (int q2 = 0; q2 < 4; ++q2)
        Z[ZIDX(base + q1 * Q1 + q2 * Q2)] = c[q1][q2];
  }
}

// single stage 6 (Q=1): j=0 -> all twiddles = 1 (pure DFT4s)
__device__ __forceinline__ void s6_fwd(float2* Z, int tid, int nthr) {
  for (int idx = tid; idx < FN / 4; idx += nthr) {
    const int base = 4 * idx;
    float2 c0 = Z[ZIDX(base)], c1 = Z[ZIDX(base + 1)];
    float2 c2 = Z[ZIDX(base + 2)], c3 = Z[ZIDX(base + 3)];
    float2 t0 = cadd(c0, c2), t1 = csub(c0, c2), t2 = cadd(c1, c3);
    float2 t3 = make_float2(c1.y - c3.y, -(c1.x - c3.x));
    Z[ZIDX(base)]     = cadd(t0, t2);
    Z[ZIDX(base + 1)] = cadd(t1, t3);
    Z[ZIDX(base + 2)] = csub(t0, t2);
    Z[ZIDX(base + 3)] = csub(t1, t3);
  }
}
__device__ __forceinline__ void s6_inv(float2* Z, int tid, int nthr) {
  for (int idx = tid; idx < FN / 4; idx += nthr) {
    const int base = 4 * idx;
    float2 u0 = Z[ZIDX(base)], u1 = Z[ZIDX(base + 1)];
    float2 u2 = Z[ZIDX(base + 2)], u3 = Z[ZIDX(base + 3)];
    float2 s0 = cadd(u0, u2), s1 = csub(u0, u2), s2 = cadd(u1, u3);
    float2 s3 = make_float2(-(u1.y - u3.y), u1.x - u3.x);
    Z[ZIDX(base)]     = cadd(s0, s2);
    Z[ZIDX(base + 1)] = cadd(s1, s3);
    Z[ZIDX(base + 2)] = csub(s0, s2);
    Z[ZIDX(base + 3)] = csub(s1, s3);
  }
}

__device__ void fft_fwd(float2* Z, const float2* __restrict__ tw, int tid, int nthr) {
  ds_fwd<4096, 1>(Z, tw, tid, nthr);   __syncthreads();   // stages 0,1
  ds_fwd<256, 16>(Z, tw, tid, nthr);   __syncthreads();   // stages 2,3
  ds_fwd<16, 256>(Z, tw, tid, nthr);   __syncthreads();   // stages 4,5
  s6_fwd(Z, tid, nthr);                __syncthreads();   // stage 6
}
__device__ void fft_inv(float2* Z, const float2* __restrict__ tw, int tid, int nthr) {
  s6_inv(Z, tid, nthr);                __syncthreads();
  ds_inv<16, 256>(Z, tw, tid, nthr);   __syncthreads();
  ds_inv<256, 16>(Z, tw, tid, nthr);   __syncthreads();
  ds_inv<4096, 1>(Z, tw, tid, nthr);   __syncthreads();
}

// twiddle tables: tw[e] = exp(-2 pi i e / 16384), tau[k] = exp(-i pi k / 16384)
__global__ void k_tw(float2* __restrict__ tw, float2* __restrict__ tau) {
  const int i = blockIdx.x * 256 + threadIdx.x;
  if (i < 12288) {
    const float ang = -6.283185307179586f * (float)i / 16384.0f;
    tw[i] = make_float2(cosf(ang), sinf(ang));
  }
  if (i <= 16384) {
    const float ang = -3.1415926535897932f * (float)i / 16384.0f;
    tau[i] = make_float2(cosf(ang), sinf(ang));
  }
}

// ---------------- kernel a construction (unchanged) ----------
__global__ void k_bands(const float* __restrict__ x,
                        const float* __restrict__ W1, const float* __restrict__ b1,
                        const float* __restrict__ W2, const float* __restrict__ b2,
                        const float* __restrict__ W3, const float* __restrict__ b3,
                        float* __restrict__ bands) {
  const int j = blockIdx.y;
  __shared__ float w2s[4096];
  __shared__ float w1s[64], b1s[64], b2s[64], w3s[64];
  for (int i = threadIdx.x; i < 4096; i += 256) w2s[i] = W2[j * 4096 + i];
  if (threadIdx.x < 64) {
    w1s[threadIdx.x] = W1[j * 64 + threadIdx.x];
    b1s[threadIdx.x] = b1[j * 64 + threadIdx.x];
    b2s[threadIdx.x] = b2[j * 64 + threadIdx.x];
    w3s[threadIdx.x] = W3[j * 64 + threadIdx.x];
  }
  __syncthreads();
  const int k = blockIdx.x * 256 + threadIdx.x;
  if (k >= 2049) return;
  const float xc = x[8 * k];
  float h1[64];
  #pragma unroll
  for (int o = 0; o < 64; ++o) h1[o] = tanhf(w1s[o] * xc + b1s[o]);
  float outv = b3[j];
  for (int o = 0; o < 64; ++o) {
    float a0 = 0.f, a1 = 0.f, a2 = 0.f, a3 = 0.f;
    #pragma unroll
    for (int c = 0; c < 64; c += 4) {
      a0 += w2s[o * 64 + c] * h1[c];
      a1 += w2s[o * 64 + c + 1] * h1[c + 1];
      a2 += w2s[o * 64 + c + 2] * h1[c + 2];
      a3 += w2s[o * 64 + c + 3] * h1[c + 3];
    }
    outv += w3s[o] * tanhf(b2s[o] + ((a0 + a1) + (a2 + a3)));
  }
  bands[j * 2049 + k] = outv;
}

// fused interp chain -> a in fp32, length 16385
__global__ void k_interp(const float* __restrict__ bands, float* __restrict__ af32) {
  __shared__ float s1[4097];
  __shared__ float s2[8193];
  const int tid = threadIdx.x;
  const float* bd0 = bands;
  const float* bd1 = bands + 2049;
  const float* bd2 = bands + 2 * 2049;
  for (int i = tid; i < 4097; i += 1024) {
    float v = (i & 1) ? 0.5f * (bd0[i >> 1] + bd0[(i >> 1) + 1]) : bd0[i >> 1];
    if (i >= 512 && i < 2561) v = bd1[i - 512];
    s1[i] = v;
  }
  __syncthreads();
  for (int i = tid; i < 8193; i += 1024) {
    float v = (i & 1) ? 0.5f * (s1[i >> 1] + s1[(i >> 1) + 1]) : s1[i >> 1];
    if (i >= 1024 && i < 3073) v = bd2[i - 1024];
    s2[i] = v;
  }
  __syncthreads();
  for (int i = tid; i < 16385; i += 1024) {
    float v = (i & 1) ? 0.5f * (s2[i >> 1] + s2[(i >> 1) + 1]) : s2[i >> 1];
    af32[i] = v;
  }
}

// A-hat: Ahat[k] = rfft_32768(a_pad)[k] / 16384, natural order, k in [0,16384].
__global__ __launch_bounds__(1024, 1) void k_ahat(const float* __restrict__ af32,
                                                  const float2* __restrict__ tw,
                                                  const float2* __restrict__ tau,
                                                  float2* __restrict__ Ahat) {
  __shared__ float2 Z[ZPAD];
  const int tid = threadIdx.x;
  for (int n = tid; n < FN; n += 1024) {
    float2 v = make_float2(0.f, 0.f);
    if (n < 8192)       v = make_float2(af32[2 * n], af32[2 * n + 1]);
    else if (n == 8192) v = make_float2(af32[16384], 0.f);
    Z[ZIDX(n)] = v;
  }
  __syncthreads();
  fft_fwd(Z, tw, tid, 1024);
  const float sc = 1.0f / 16384.0f;
  for (int k = tid; k <= 16384; k += 1024) {
    float2 A;
    if (k == 0) {
      float2 z0 = Z[ZIDX(0)];
      A = make_float2((z0.x + z0.y) * sc, 0.f);
    } else if (k == 16384) {
      float2 z0 = Z[ZIDX(0)];
      A = make_float2((z0.x - z0.y) * sc, 0.f);
    } else if (k == 8192) {
      float2 z8 = Z[ZIDX(rev4_14(8192))];
      A = make_float2(z8.x * sc, -z8.y * sc);
    } else {
      const int kc = 16384 - k;
      float2 Zk = Z[ZIDX(rev4_14(k))];
      float2 Zc = Z[ZIDX(rev4_14(kc))];
      float2 E = make_float2(0.5f * (Zk.x + Zc.x), 0.5f * (Zk.y - Zc.y));
      float2 D = make_float2(Zk.x - Zc.x, Zk.y + Zc.y);
      float2 O = make_float2(0.5f * D.y, -0.5f * D.x);
      float2 tk = tau[k];                   // exp(-i pi k/N)
      float2 tO = cmul(tk, O);
      A = make_float2((E.x + tO.x) * sc, (E.y + tO.y) * sc);
    }
    Ahat[k] = A;
  }
}

// Main conv kernel: one batch row per block (formulas verbatim from R10).
__global__ __launch_bounds__(1024, 1) void k_conv(const float* __restrict__ u,
                                                  const float2* __restrict__ Ahat,
                                                  const float2* __restrict__ tw,
                                                  const float2* __restrict__ tau,
                                                  float* __restrict__ out) {
  __shared__ float2 Z[ZPAD];
  const int tid = threadIdx.x;
  const int b = blockIdx.x;
  const float* ub = u + (size_t)b * NN;

  for (int n = tid; n < FN; n += 1024) {
    float2 v = make_float2(0.f, 0.f);
    if (n == 0)          v = make_float2(ub[8192], 0.f);
    else if (n >= 12288) {
      const int m = n - 12288;
      v = make_float2(ub[2 * m], ub[2 * m + 1]);
    }
    Z[ZIDX(n)] = v;
  }
  __syncthreads();

  fft_fwd(Z, tw, tid, 1024);

  // spectral multiply in the digit-reversed domain (pairs bijective, no sync)
  for (int i = tid; i < 8192; i += 1024) {
    if (i == 0) {
      float2 z0 = Z[ZIDX(0)];
      float X0 = z0.x + z0.y;
      float XN = z0.x - z0.y;
      float Y0 = X0 * Ahat[0].x;
      float YN = XN * Ahat[16384].x;
      Z[ZIDX(0)] = make_float2(0.5f * (Y0 + YN), 0.5f * (Y0 - YN));
      const int r8 = rev4_14(8192);
      float2 z8 = Z[ZIDX(r8)];
      float2 X8 = make_float2(z8.x, -z8.y);
      float2 Y8 = cmul(X8, Ahat[8192]);
      Z[ZIDX(r8)] = make_float2(Y8.x, -Y8.y);
    } else {
      const int k = i, kc = 16384 - i;
      const int rk = ZIDX(rev4_14(k)), rkc = ZIDX(rev4_14(kc));
      float2 Zk = Z[rk], Zc = Z[rkc];
      float2 E = make_float2(0.5f * (Zk.x + Zc.x), 0.5f * (Zk.y - Zc.y));
      float2 D = make_float2(Zk.x - Zc.x, Zk.y + Zc.y);
      float2 O = make_float2(0.5f * D.y, -0.5f * D.x);
      float2 tk = tau[k];                       // exp(-i pi k/N)
      float2 tO = cmul(tk, O);
      float2 Xk = make_float2(E.x + tO.x, E.y + tO.y);
      float2 Xc = make_float2(E.x - tO.x, -(E.y - tO.y));
      float2 Yk = cmul(Xk, Ahat[k]);
      float2 Y2 = cmul(Xc, Ahat[kc]);
      float2 Ep = make_float2(0.5f * (Yk.x + Y2.x), 0.5f * (Yk.y - Y2.y));
      float2 D2 = make_float2(0.5f * (Yk.x - Y2.x), 0.5f * (Yk.y + Y2.y));
      float2 tb = make_float2(tk.x, -tk.y);     // exp(+i pi k/N)
      float2 Op = cmul(tb, D2);
      Z[rk]  = make_float2(Ep.x - Op.y, Ep.y + Op.x);
      Z[rkc] = make_float2(Ep.x + Op.y, -Ep.y + Op.x);
    }
  }
  __syncthreads();

  fft_inv(Z, tw, tid, 1024);

  float* ob = out + (size_t)b * NN;
  for (int n = tid; n <= 4096; n += 1024) {
    float2 w = Z[ZIDX(n)];
    if (n < 4096) {
      ob[2 * n]     = w.x;
      ob[2 * n + 1] = w.y;
    } else {
      ob[8192] = w.x;
    }
  }
}

extern "C" void kernel_launch(void* const* d_in, const int* in_sizes, int n_in,
                              void* d_out, int out_size, void* d_ws, size_t ws_size,
                              hipStream_t stream) {
  (void)in_sizes; (void)n_in; (void)out_size; (void)ws_size;
  const float* u  = (const float*)d_in[0];
  const float* x  = (const float*)d_in[1];
  const float* W1 = (const float*)d_in[2];
  const float* b1 = (const float*)d_in[3];
  const float* W2 = (const float*)d_in[4];
  const float* b2 = (const float*)d_in[5];
  const float* W3 = (const float*)d_in[6];
  const float* b3 = (const float*)d_in[7];
  float* out = (float*)d_out;
  char*  ws  = (char*)d_ws;

  float*  bands = (float*)(ws + OFF_BANDS);
  float*  af32  = (float*)(ws + OFF_AF32);
  float2* Ahat  = (float2*)(ws + OFF_AHAT);
  float2* tw    = (float2*)(ws + OFF_TW);
  float2* tau   = (float2*)(ws + OFF_TAU);

  k_tw<<<65, 256, 0, stream>>>(tw, tau);
  k_bands<<<dim3(9, 3), 256, 0, stream>>>(x, W1, b1, W2, b2, W3, b3, bands);
  k_interp<<<1, 1024, 0, stream>>>(bands, af32);
  k_ahat<<<1, 1024, 0, stream>>>(af32, tw, tau, Ahat);
  k_conv<<<1024, 1024, 0, stream>>>(u, Ahat, tw, tau, out);
}

// Round 12
// 263.988 us; speedup vs baseline: 1.2536x; 1.1061x over previous
//
#include <hip/hip_runtime.h>

#define NN  8193       // output cols per row; u length
#define FN  16384      // complex FFT length (real conv length 32768)
#define NTHR 512       // threads per FFT block (8 waves -> VGPR cap 256, no spill)

// LDS swizzle-pad. Bank-pair stride classes (mod 16): 1->1, 4->4, 64->5,
// 256->4, 1024->1 (the rev-gather class that was 0 under the old pad).
// Injective (strictly increasing). Max ZIDX(16383) = 17676.
#define ZIDX(i) ((i) + ((i) >> 4) + ((i) >> 6) + ((i) >> 10))
#define ZPAD 17680

// workspace byte offsets (256-aligned)
#define OFF_BANDS 0u        // 3*2049*4 = 24588
#define OFF_AF32  24832u    // 16385*4 = 65540
#define OFF_AHAT  90624u    // 16385*8 = 131080
#define OFF_TW    221952u   // 12288*8 = 98304  (w_N^e, e in [0,12288))
#define OFF_TAU   320256u   // 16385*8 = 131080 (exp(-i pi k/N), k in [0,16384])

__device__ __forceinline__ float2 cmul(float2 a, float2 b) {
  return make_float2(a.x * b.x - a.y * b.y, a.x * b.y + a.y * b.x);
}
__device__ __forceinline__ float2 cadd(float2 a, float2 b) { return make_float2(a.x + b.x, a.y + b.y); }
__device__ __forceinline__ float2 csub(float2 a, float2 b) { return make_float2(a.x - b.x, a.y - b.y); }

// base-4 digit reversal of 7 digits (14 bits)
__device__ __forceinline__ int rev4_14(int k) {
  int r = 0;
  #pragma unroll
  for (int i = 0; i < 7; ++i) { r = (r << 2) | (k & 3); k >>= 2; }
  return r;
}

// ---- fused double radix-4 stage, forward (R11-verified formulas) ----
template<int Q1, int M1>
__device__ __forceinline__ void ds_fwd(float2* Z, const float2* __restrict__ tw,
                                       int tid) {
  constexpr int Q2 = Q1 >> 2;
  constexpr int M2 = M1 << 2;
  #pragma unroll 1
  for (int t = tid; t < 1024; t += NTHR) {
    const int b1 = t / Q2;
    const int j2 = t & (Q2 - 1);
    const int base = b1 * 4 * Q1 + j2;
    float2 c[4][4];  // [q1][q2]
    #pragma unroll
    for (int q1 = 0; q1 < 4; ++q1)
      #pragma unroll
      for (int q2 = 0; q2 < 4; ++q2)
        c[q1][q2] = Z[ZIDX(base + q2 * Q2 + q1 * Q1)];
    #pragma unroll
    for (int q2 = 0; q2 < 4; ++q2) {
      const int e = (j2 + q2 * Q2) * M1;
      const float2 w1 = tw[e], w2 = tw[2 * e], w3 = tw[3 * e];
      float2 c0 = c[0][q2], c1 = c[1][q2], c2 = c[2][q2], c3 = c[3][q2];
      float2 t0 = cadd(c0, c2), t1 = csub(c0, c2), t2 = cadd(c1, c3);
      float2 t3 = make_float2(c1.y - c3.y, -(c1.x - c3.x));   // -i*(c1-c3)
      c[0][q2] = cadd(t0, t2);
      c[1][q2] = cmul(w1, cadd(t1, t3));
      c[2][q2] = cmul(w2, csub(t0, t2));
      c[3][q2] = cmul(w3, csub(t1, t3));
    }
    const int e2 = j2 * M2;
    const float2 v1 = tw[e2], v2 = tw[2 * e2], v3 = tw[3 * e2];
    #pragma unroll
    for (int p1 = 0; p1 < 4; ++p1) {
      float2 c0 = c[p1][0], c1 = c[p1][1], c2 = c[p1][2], c3 = c[p1][3];
      float2 t0 = cadd(c0, c2), t1 = csub(c0, c2), t2 = cadd(c1, c3);
      float2 t3 = make_float2(c1.y - c3.y, -(c1.x - c3.x));
      c[p1][0] = cadd(t0, t2);
      c[p1][1] = cmul(v1, cadd(t1, t3));
      c[p1][2] = cmul(v2, csub(t0, t2));
      c[p1][3] = cmul(v3, csub(t1, t3));
    }
    #pragma unroll
    for (int p1 = 0; p1 < 4; ++p1)
      #pragma unroll
      for (int p2 = 0; p2 < 4; ++p2)
        Z[ZIDX(base + p1 * Q1 + p2 * Q2)] = c[p1][p2];
  }
}

// ---- fused double stage, exact adjoint ----
template<int Q1, int M1>
__device__ __forceinline__ void ds_inv(float2* Z, const float2* __restrict__ tw,
                                       int tid) {
  constexpr int Q2 = Q1 >> 2;
  constexpr int M2 = M1 << 2;
  #pragma unroll 1
  for (int t = tid; t < 1024; t += NTHR) {
    const int b1 = t / Q2;
    const int j2 = t & (Q2 - 1);
    const int base = b1 * 4 * Q1 + j2;
    float2 c[4][4];  // [p1][p2]
    #pragma unroll
    for (int p1 = 0; p1 < 4; ++p1)
      #pragma unroll
      for (int p2 = 0; p2 < 4; ++p2)
        c[p1][p2] = Z[ZIDX(base + p1 * Q1 + p2 * Q2)];
    const int e2 = j2 * M2;
    float2 v1 = tw[e2], v2 = tw[2 * e2], v3 = tw[3 * e2];
    v1.y = -v1.y; v2.y = -v2.y; v3.y = -v3.y;
    #pragma unroll
    for (int p1 = 0; p1 < 4; ++p1) {
      float2 u0 = c[p1][0];
      float2 u1 = cmul(v1, c[p1][1]);
      float2 u2 = cmul(v2, c[p1][2]);
      float2 u3 = cmul(v3, c[p1][3]);
      float2 s0 = cadd(u0, u2), s1 = csub(u0, u2), s2 = cadd(u1, u3);
      float2 s3 = make_float2(-(u1.y - u3.y), u1.x - u3.x);  // +i*(u1-u3)
      c[p1][0] = cadd(s0, s2);
      c[p1][1] = cadd(s1, s3);
      c[p1][2] = csub(s0, s2);
      c[p1][3] = csub(s1, s3);
    }
    #pragma unroll
    for (int q2 = 0; q2 < 4; ++q2) {
      const int e = (j2 + q2 * Q2) * M1;
      float2 w1 = tw[e], w2 = tw[2 * e], w3 = tw[3 * e];
      w1.y = -w1.y; w2.y = -w2.y; w3.y = -w3.y;
      float2 u0 = c[0][q2];
      float2 u1 = cmul(w1, c[1][q2]);
      float2 u2 = cmul(w2, c[2][q2]);
      float2 u3 = cmul(w3, c[3][q2]);
      float2 s0 = cadd(u0, u2), s1 = csub(u0, u2), s2 = cadd(u1, u3);
      float2 s3 = make_float2(-(u1.y - u3.y), u1.x - u3.x);
      c[0][q2] = cadd(s0, s2);
      c[1][q2] = cadd(s1, s3);
      c[2][q2] = csub(s0, s2);
      c[3][q2] = csub(s1, s3);
    }
    #pragma unroll
    for (int q1 = 0; q1 < 4; ++q1)
      #pragma unroll
      for (int q2 = 0; q2 < 4; ++q2)
        Z[ZIDX(base + q1 * Q1 + q2 * Q2)] = c[q1][q2];
  }
}

// single stage 6 (Q=1): all twiddles = 1
__device__ __forceinline__ void s6_fwd(float2* Z, int tid) {
  #pragma unroll 1
  for (int idx = tid; idx < FN / 4; idx += NTHR) {
    const int base = 4 * idx;
    float2 c0 = Z[ZIDX(base)], c1 = Z[ZIDX(base + 1)];
    float2 c2 = Z[ZIDX(base + 2)], c3 = Z[ZIDX(base + 3)];
    float2 t0 = cadd(c0, c2), t1 = csub(c0, c2), t2 = cadd(c1, c3);
    float2 t3 = make_float2(c1.y - c3.y, -(c1.x - c3.x));
    Z[ZIDX(base)]     = cadd(t0, t2);
    Z[ZIDX(base + 1)] = cadd(t1, t3);
    Z[ZIDX(base + 2)] = csub(t0, t2);
    Z[ZIDX(base + 3)] = csub(t1, t3);
  }
}
__device__ __forceinline__ void s6_inv(float2* Z, int tid) {
  #pragma unroll 1
  for (int idx = tid; idx < FN / 4; idx += NTHR) {
    const int base = 4 * idx;
    float2 u0 = Z[ZIDX(base)], u1 = Z[ZIDX(base + 1)];
    float2 u2 = Z[ZIDX(base + 2)], u3 = Z[ZIDX(base + 3)];
    float2 s0 = cadd(u0, u2), s1 = csub(u0, u2), s2 = cadd(u1, u3);
    float2 s3 = make_float2(-(u1.y - u3.y), u1.x - u3.x);
    Z[ZIDX(base)]     = cadd(s0, s2);
    Z[ZIDX(base + 1)] = cadd(s1, s3);
    Z[ZIDX(base + 2)] = csub(s0, s2);
    Z[ZIDX(base + 3)] = csub(s1, s3);
  }
}

__device__ void fft_fwd(float2* Z, const float2* __restrict__ tw, int tid) {
  ds_fwd<4096, 1>(Z, tw, tid);   __syncthreads();   // stages 0,1
  ds_fwd<256, 16>(Z, tw, tid);   __syncthreads();   // stages 2,3
  ds_fwd<16, 256>(Z, tw, tid);   __syncthreads();   // stages 4,5
  s6_fwd(Z, tid);                __syncthreads();   // stage 6
}
__device__ void fft_inv(float2* Z, const float2* __restrict__ tw, int tid) {
  s6_inv(Z, tid);                __syncthreads();
  ds_inv<16, 256>(Z, tw, tid);   __syncthreads();
  ds_inv<256, 16>(Z, tw, tid);   __syncthreads();
  ds_inv<4096, 1>(Z, tw, tid);   __syncthreads();
}

// twiddle tables: tw[e] = exp(-2 pi i e / 16384), tau[k] = exp(-i pi k / 16384)
__global__ void k_tw(float2* __restrict__ tw, float2* __restrict__ tau) {
  const int i = blockIdx.x * 256 + threadIdx.x;
  if (i < 12288) {
    const float ang = -6.283185307179586f * (float)i / 16384.0f;
    tw[i] = make_float2(cosf(ang), sinf(ang));
  }
  if (i <= 16384) {
    const float ang = -3.1415926535897932f * (float)i / 16384.0f;
    tau[i] = make_float2(cosf(ang), sinf(ang));
  }
}

// ---------------- kernel a construction (unchanged) ----------
__global__ void k_bands(const float* __restrict__ x,
                        const float* __restrict__ W1, const float* __restrict__ b1,
                        const float* __restrict__ W2, const float* __restrict__ b2,
                        const float* __restrict__ W3, const float* __restrict__ b3,
                        float* __restrict__ bands) {
  const int j = blockIdx.y;
  __shared__ float w2s[4096];
  __shared__ float w1s[64], b1s[64], b2s[64], w3s[64];
  for (int i = threadIdx.x; i < 4096; i += 256) w2s[i] = W2[j * 4096 + i];
  if (threadIdx.x < 64) {
    w1s[threadIdx.x] = W1[j * 64 + threadIdx.x];
    b1s[threadIdx.x] = b1[j * 64 + threadIdx.x];
    b2s[threadIdx.x] = b2[j * 64 + threadIdx.x];
    w3s[threadIdx.x] = W3[j * 64 + threadIdx.x];
  }
  __syncthreads();
  const int k = blockIdx.x * 256 + threadIdx.x;
  if (k >= 2049) return;
  const float xc = x[8 * k];
  float h1[64];
  #pragma unroll
  for (int o = 0; o < 64; ++o) h1[o] = tanhf(w1s[o] * xc + b1s[o]);
  float outv = b3[j];
  for (int o = 0; o < 64; ++o) {
    float a0 = 0.f, a1 = 0.f, a2 = 0.f, a3 = 0.f;
    #pragma unroll
    for (int c = 0; c < 64; c += 4) {
      a0 += w2s[o * 64 + c] * h1[c];
      a1 += w2s[o * 64 + c + 1] * h1[c + 1];
      a2 += w2s[o * 64 + c + 2] * h1[c + 2];
      a3 += w2s[o * 64 + c + 3] * h1[c + 3];
    }
    outv += w3s[o] * tanhf(b2s[o] + ((a0 + a1) + (a2 + a3)));
  }
  bands[j * 2049 + k] = outv;
}

// fused interp chain -> a in fp32, length 16385
__global__ void k_interp(const float* __restrict__ bands, float* __restrict__ af32) {
  __shared__ float s1[4097];
  __shared__ float s2[8193];
  const int tid = threadIdx.x;
  const float* bd0 = bands;
  const float* bd1 = bands + 2049;
  const float* bd2 = bands + 2 * 2049;
  for (int i = tid; i < 4097; i += 1024) {
    float v = (i & 1) ? 0.5f * (bd0[i >> 1] + bd0[(i >> 1) + 1]) : bd0[i >> 1];
    if (i >= 512 && i < 2561) v = bd1[i - 512];
    s1[i] = v;
  }
  __syncthreads();
  for (int i = tid; i < 8193; i += 1024) {
    float v = (i & 1) ? 0.5f * (s1[i >> 1] + s1[(i >> 1) + 1]) : s1[i >> 1];
    if (i >= 1024 && i < 3073) v = bd2[i - 1024];
    s2[i] = v;
  }
  __syncthreads();
  for (int i = tid; i < 16385; i += 1024) {
    float v = (i & 1) ? 0.5f * (s2[i >> 1] + s2[(i >> 1) + 1]) : s2[i >> 1];
    af32[i] = v;
  }
}

// A-hat: Ahat[k] = rfft_32768(a_pad)[k] / 16384, natural order, k in [0,16384].
__global__ __launch_bounds__(NTHR, 2) void k_ahat(const float* __restrict__ af32,
                                                  const float2* __restrict__ tw,
                                                  const float2* __restrict__ tau,
                                                  float2* __restrict__ Ahat) {
  __shared__ float2 Z[ZPAD];
  const int tid = threadIdx.x;
  for (int n = tid; n < FN; n += NTHR) {
    float2 v = make_float2(0.f, 0.f);
    if (n < 8192)       v = make_float2(af32[2 * n], af32[2 * n + 1]);
    else if (n == 8192) v = make_float2(af32[16384], 0.f);
    Z[ZIDX(n)] = v;
  }
  __syncthreads();
  fft_fwd(Z, tw, tid);
  const float sc = 1.0f / 16384.0f;
  for (int k = tid; k <= 16384; k += NTHR) {
    float2 A;
    if (k == 0) {
      float2 z0 = Z[ZIDX(0)];
      A = make_float2((z0.x + z0.y) * sc, 0.f);
    } else if (k == 16384) {
      float2 z0 = Z[ZIDX(0)];
      A = make_float2((z0.x - z0.y) * sc, 0.f);
    } else if (k == 8192) {
      float2 z8 = Z[ZIDX(rev4_14(8192))];
      A = make_float2(z8.x * sc, -z8.y * sc);
    } else {
      const int kc = 16384 - k;
      float2 Zk = Z[ZIDX(rev4_14(k))];
      float2 Zc = Z[ZIDX(rev4_14(kc))];
      float2 E = make_float2(0.5f * (Zk.x + Zc.x), 0.5f * (Zk.y - Zc.y));
      float2 D = make_float2(Zk.x - Zc.x, Zk.y + Zc.y);
      float2 O = make_float2(0.5f * D.y, -0.5f * D.x);
      float2 tk = tau[k];
      float2 tO = cmul(tk, O);
      A = make_float2((E.x + tO.x) * sc, (E.y + tO.y) * sc);
    }
    Ahat[k] = A;
  }
}

// Main conv kernel: one batch row per block (formulas verbatim from R10/R11).
__global__ __launch_bounds__(NTHR, 2) void k_conv(const float* __restrict__ u,
                                                  const float2* __restrict__ Ahat,
                                                  const float2* __restrict__ tw,
                                                  const float2* __restrict__ tau,
                                                  float* __restrict__ out) {
  __shared__ float2 Z[ZPAD];
  const int tid = threadIdx.x;
  const int b = blockIdx.x;
  const float* ub = u + (size_t)b * NN;

  for (int n = tid; n < FN; n += NTHR) {
    float2 v = make_float2(0.f, 0.f);
    if (n == 0)          v = make_float2(ub[8192], 0.f);
    else if (n >= 12288) {
      const int m = n - 12288;
      v = make_float2(ub[2 * m], ub[2 * m + 1]);
    }
    Z[ZIDX(n)] = v;
  }
  __syncthreads();

  fft_fwd(Z, tw, tid);

  // spectral multiply in the digit-reversed domain (pairs bijective, no sync)
  for (int i = tid; i < 8192; i += NTHR) {
    if (i == 0) {
      float2 z0 = Z[ZIDX(0)];
      float X0 = z0.x + z0.y;
      float XN = z0.x - z0.y;
      float Y0 = X0 * Ahat[0].x;
      float YN = XN * Ahat[16384].x;
      Z[ZIDX(0)] = make_float2(0.5f * (Y0 + YN), 0.5f * (Y0 - YN));
      const int r8 = rev4_14(8192);
      float2 z8 = Z[ZIDX(r8)];
      float2 X8 = make_float2(z8.x, -z8.y);
      float2 Y8 = cmul(X8, Ahat[8192]);
      Z[ZIDX(r8)] = make_float2(Y8.x, -Y8.y);
    } else {
      const int k = i, kc = 16384 - i;
      const int rk = ZIDX(rev4_14(k)), rkc = ZIDX(rev4_14(kc));
      float2 Zk = Z[rk], Zc = Z[rkc];
      float2 E = make_float2(0.5f * (Zk.x + Zc.x), 0.5f * (Zk.y - Zc.y));
      float2 D = make_float2(Zk.x - Zc.x, Zk.y + Zc.y);
      float2 O = make_float2(0.5f * D.y, -0.5f * D.x);
      float2 tk = tau[k];
      float2 tO = cmul(tk, O);
      float2 Xk = make_float2(E.x + tO.x, E.y + tO.y);
      float2 Xc = make_float2(E.x - tO.x, -(E.y - tO.y));
      float2 Yk = cmul(Xk, Ahat[k]);
      float2 Y2 = cmul(Xc, Ahat[kc]);
      float2 Ep = make_float2(0.5f * (Yk.x + Y2.x), 0.5f * (Yk.y - Y2.y));
      float2 D2 = make_float2(0.5f * (Yk.x - Y2.x), 0.5f * (Yk.y + Y2.y));
      float2 tb = make_float2(tk.x, -tk.y);
      float2 Op = cmul(tb, D2);
      Z[rk]  = make_float2(Ep.x - Op.y, Ep.y + Op.x);
      Z[rkc] = make_float2(Ep.x + Op.y, -Ep.y + Op.x);
    }
  }
  __syncthreads();

  fft_inv(Z, tw, tid);

  float* ob = out + (size_t)b * NN;
  for (int n = tid; n <= 4096; n += NTHR) {
    float2 w = Z[ZIDX(n)];
    if (n < 4096) {
      ob[2 * n]     = w.x;
      ob[2 * n + 1] = w.y;
    } else {
      ob[8192] = w.x;
    }
  }
}

extern "C" void kernel_launch(void* const* d_in, const int* in_sizes, int n_in,
                              void* d_out, int out_size, void* d_ws, size_t ws_size,
                              hipStream_t stream) {
  (void)in_sizes; (void)n_in; (void)out_size; (void)ws_size;
  const float* u  = (const float*)d_in[0];
  const float* x  = (const float*)d_in[1];
  const float* W1 = (const float*)d_in[2];
  const float* b1 = (const float*)d_in[3];
  const float* W2 = (const float*)d_in[4];
  const float* b2 = (const float*)d_in[5];
  const float* W3 = (const float*)d_in[6];
  const float* b3 = (const float*)d_in[7];
  float* out = (float*)d_out;
  char*  ws  = (char*)d_ws;

  float*  bands = (float*)(ws + OFF_BANDS);
  float*  af32  = (float*)(ws + OFF_AF32);
  float2* Ahat  = (float2*)(ws + OFF_AHAT);
  float2* tw    = (float2*)(ws + OFF_TW);
  float2* tau   = (float2*)(ws + OFF_TAU);

  k_tw<<<65, 256, 0, stream>>>(tw, tau);
  k_bands<<<dim3(9, 3), 256, 0, stream>>>(x, W1, b1, W2, b2, W3, b3, bands);
  k_interp<<<1, 1024, 0, stream>>>(bands, af32);
  k_ahat<<<1, NTHR, 0, stream>>>(af32, tw, tau, Ahat);
  k_conv<<<1024, NTHR, 0, stream>>>(u, Ahat, tw, tau, out);
}